// Round 1
// baseline (544.459 us; speedup 1.0000x reference)
//
#include <hip/hip_runtime.h>
#include <hip/hip_bf16.h>

#define N_NODES 50000
#define N_EDGES 600000
#define F_IN    92
#define HID     32
#define HEADS   8
#define D1      256
#define G_GRAPHS 512
#define EPSV    1e-5f
#define NCHUNK  49   // ceil(50000/1024)

// ---------------- CSR build ----------------

__global__ void k_deg(const int* __restrict__ ei, const float* __restrict__ ea,
                      int* __restrict__ deg, float* __restrict__ easum) {
    int e = blockIdx.x * 256 + threadIdx.x;
    if (e < N_EDGES) {
        int d = ei[N_EDGES + e];
        atomicAdd(&deg[d], 1);
        atomicAdd(&easum[d], ea[e]);
    }
}

__global__ void k_partial(const int* __restrict__ deg, int* __restrict__ partials) {
    int b = blockIdx.x;
    int s = 0;
    for (int j = 0; j < 4; ++j) {
        int i = b * 1024 + j * 256 + threadIdx.x;
        if (i < N_NODES) s += deg[i];
    }
    for (int off = 32; off; off >>= 1) s += __shfl_down(s, off, 64);
    __shared__ int sm[4];
    if ((threadIdx.x & 63) == 0) sm[threadIdx.x >> 6] = s;
    __syncthreads();
    if (threadIdx.x == 0) partials[b] = sm[0] + sm[1] + sm[2] + sm[3];
}

__global__ void k_scanp(const int* __restrict__ partials, int* __restrict__ poff) {
    if (threadIdx.x == 0 && blockIdx.x == 0) {
        int acc = 0;
        for (int b = 0; b < NCHUNK; ++b) { poff[b] = acc; acc += partials[b]; }
    }
}

__global__ void k_scanc(const int* __restrict__ deg, const int* __restrict__ poff,
                        int* __restrict__ row_off, int* __restrict__ cursor) {
    int b = blockIdx.x;
    int t = threadIdx.x;
    int base_i = b * 1024 + t * 4;
    int v[4]; int s = 0;
    #pragma unroll
    for (int j = 0; j < 4; ++j) {
        int i = base_i + j;
        v[j] = (i < N_NODES) ? deg[i] : 0;
        s += v[j];
    }
    __shared__ int sm[256];
    sm[t] = s;
    __syncthreads();
    int val = s;
    for (int off = 1; off < 256; off <<= 1) {
        int add = (t >= off) ? sm[t - off] : 0;
        __syncthreads();
        val += add;
        sm[t] = val;
        __syncthreads();
    }
    int base = poff[b] + (val - s);   // exclusive prefix
    #pragma unroll
    for (int j = 0; j < 4; ++j) {
        int i = base_i + j;
        if (i < N_NODES) { row_off[i] = base; cursor[i] = base; }
        base += v[j];
    }
}

__global__ void k_fill(const int* __restrict__ ei, const float* __restrict__ ea,
                       int* __restrict__ cursor, int* __restrict__ adj_src,
                       float* __restrict__ adj_ea) {
    int e = blockIdx.x * 256 + threadIdx.x;
    if (e < N_EDGES) {
        int d = ei[N_EDGES + e];
        int pos = atomicAdd(&cursor[d], 1);
        adj_src[pos] = ei[e];
        adj_ea[pos] = ea[e];
    }
}

__global__ void k_prep(const float* __restrict__ We1, const float* __restrict__ ae1,
                       const float* __restrict__ We2, const float* __restrict__ ae2,
                       float* __restrict__ wedot) {
    int t = threadIdx.x;
    if (t < HEADS) {
        float a = 0.f;
        for (int c = 0; c < HID; ++c) a += We1[t * HID + c] * ae1[t * HID + c];
        wedot[t] = a;
    } else if (t == HEADS) {
        float a = 0.f;
        for (int c = 0; c < HID; ++c) a += We2[c] * ae2[c];
        wedot[HEADS] = a;
    }
}

// ---------------- conv1 ----------------

__global__ __launch_bounds__(256) void k_gemm1(const float* __restrict__ x,
                                               const float* __restrict__ W1,
                                               float* __restrict__ h1) {
    __shared__ float xs[16 * F_IN];
    int n0 = blockIdx.x * 16;
    for (int i = threadIdx.x; i < 16 * F_IN; i += 256)
        xs[i] = x[(size_t)n0 * F_IN + i];   // contiguous: r*92+k
    __syncthreads();
    int col = threadIdx.x;
    float acc[16];
    #pragma unroll
    for (int r = 0; r < 16; ++r) acc[r] = 0.f;
    for (int k = 0; k < F_IN; ++k) {
        float w = W1[k * D1 + col];
        #pragma unroll
        for (int r = 0; r < 16; ++r) acc[r] += xs[r * F_IN + k] * w;
    }
    #pragma unroll
    for (int r = 0; r < 16; ++r)
        h1[(size_t)(n0 + r) * D1 + col] = acc[r];
}

__global__ void k_alpha1(const float* __restrict__ h1, const float* __restrict__ as1,
                         const float* __restrict__ ad1, float* __restrict__ al_s,
                         float* __restrict__ al_d) {
    int n = blockIdx.x;
    int t = threadIdx.x;
    float v = h1[(size_t)n * D1 + t];
    float vs = v * as1[t];
    float vd = v * ad1[t];
    #pragma unroll
    for (int off = 16; off; off >>= 1) {
        vs += __shfl_xor(vs, off, 64);
        vd += __shfl_xor(vd, off, 64);
    }
    if ((t & 31) == 0) {
        al_s[n * HEADS + (t >> 5)] = vs;
        al_d[n * HEADS + (t >> 5)] = vd;
    }
}

__global__ __launch_bounds__(256) void k_aggr1(
        const int* __restrict__ row_off, const int* __restrict__ deg,
        const int* __restrict__ adj_src, const float* __restrict__ adj_ea,
        const float* __restrict__ easum, const float* __restrict__ h1,
        const float* __restrict__ al_s, const float* __restrict__ al_d,
        const float* __restrict__ wedot,
        const float* __restrict__ b1, const float* __restrict__ g1,
        const float* __restrict__ be1, const float* __restrict__ m1,
        const float* __restrict__ v1, float* __restrict__ h1p) {
    int n = blockIdx.x;
    int t = threadIdx.x;
    int h = t >> 5;
    float wd = wedot[h];
    float dn = al_d[n * HEADS + h];
    int r0 = row_off[n], cnt = deg[n];
    float acc = 0.f, den = 0.f;
    for (int i = 0; i < cnt; ++i) {
        int s = adj_src[r0 + i];
        float eav = adj_ea[r0 + i];
        float a = al_s[s * HEADS + h] + dn + eav * wd;
        a = a > 0.f ? a : 0.2f * a;
        float w = __expf(a);
        den += w;
        acc += w * h1[(size_t)s * D1 + t];
    }
    {   // self loop, attr = mean of incoming (0 if none)
        float la = easum[n] / (float)(cnt > 0 ? cnt : 1);
        float a = al_s[n * HEADS + h] + dn + la * wd;
        a = a > 0.f ? a : 0.2f * a;
        float w = __expf(a);
        den += w;
        acc += w * h1[(size_t)n * D1 + t];
    }
    float o = acc / den + b1[t];
    float sc = g1[t] / sqrtf(v1[t] + EPSV);
    float y = (o - m1[t]) * sc + be1[t];
    h1p[(size_t)n * D1 + t] = y > 0.f ? y : 0.f;
}

// ---------------- conv2 ----------------

__global__ void k_gemm2(const float* __restrict__ h1p, const float* __restrict__ W2,
                        float* __restrict__ h2) {
    int gid = blockIdx.x * 256 + threadIdx.x;
    if (gid >= N_NODES * HID) return;
    int n = gid >> 5, c = gid & 31;
    float acc = 0.f;
    #pragma unroll 8
    for (int k = 0; k < D1; ++k)
        acc += h1p[(size_t)n * D1 + k] * W2[k * HID + c];
    h2[gid] = acc;
}

__global__ void k_alpha2(const float* __restrict__ h2, const float* __restrict__ as2,
                         const float* __restrict__ ad2, float* __restrict__ al_s2,
                         float* __restrict__ al_d2) {
    int gid = blockIdx.x * 256 + threadIdx.x;
    int n = gid >> 5, c = gid & 31;
    if (n >= N_NODES) return;
    float v = h2[gid];
    float vs = v * as2[c];
    float vd = v * ad2[c];
    #pragma unroll
    for (int off = 16; off; off >>= 1) {
        vs += __shfl_xor(vs, off, 64);
        vd += __shfl_xor(vd, off, 64);
    }
    if (c == 0) { al_s2[n] = vs; al_d2[n] = vd; }
}

__global__ void k_aggr2(
        const int* __restrict__ row_off, const int* __restrict__ deg,
        const int* __restrict__ adj_src, const float* __restrict__ adj_ea,
        const float* __restrict__ easum, const float* __restrict__ h2,
        const float* __restrict__ al_s2, const float* __restrict__ al_d2,
        const float* __restrict__ wedot,
        const float* __restrict__ b2, const float* __restrict__ g2,
        const float* __restrict__ be2, const float* __restrict__ m2,
        const float* __restrict__ v2, const int* __restrict__ batch,
        float* __restrict__ pool, int* __restrict__ pcnt) {
    int t = threadIdx.x;
    int ln = t >> 5, c = t & 31;
    int n = blockIdx.x * 8 + ln;
    if (n >= N_NODES) return;
    float wd = wedot[HEADS];
    float dn = al_d2[n];
    int r0 = row_off[n], cnt = deg[n];
    float acc = 0.f, den = 0.f;
    for (int i = 0; i < cnt; ++i) {
        int s = adj_src[r0 + i];
        float eav = adj_ea[r0 + i];
        float a = al_s2[s] + dn + eav * wd;
        a = a > 0.f ? a : 0.2f * a;
        float w = __expf(a);
        den += w;
        acc += w * h2[(size_t)s * HID + c];
    }
    {
        float la = easum[n] / (float)(cnt > 0 ? cnt : 1);
        float a = al_s2[n] + dn + la * wd;
        a = a > 0.f ? a : 0.2f * a;
        float w = __expf(a);
        den += w;
        acc += w * h2[(size_t)n * HID + c];
    }
    float o = acc / den + b2[c];
    float sc = g2[c] / sqrtf(v2[c] + EPSV);
    float y = (o - m2[c]) * sc + be2[c];
    y = y > 0.f ? y : 0.f;
    int g = batch[n];
    atomicAdd(&pool[g * HID + c], y);
    if (c == 0) atomicAdd(&pcnt[g], 1);
}

__global__ void k_fc(const float* __restrict__ pool, const int* __restrict__ pcnt,
                     const float* __restrict__ fcW, const float* __restrict__ fcb,
                     float* __restrict__ out) {
    int g = blockIdx.x * 256 + threadIdx.x;
    if (g >= G_GRAPHS) return;
    float cg = (float)(pcnt[g] > 0 ? pcnt[g] : 1);
    float acc = 0.f;
    #pragma unroll
    for (int c = 0; c < HID; ++c) acc += pool[g * HID + c] * fcW[c];
    out[g] = acc / cg + fcb[0];
}

// ---------------- launch ----------------

extern "C" void kernel_launch(void* const* d_in, const int* in_sizes, int n_in,
                              void* d_out, int out_size, void* d_ws, size_t ws_size,
                              hipStream_t stream) {
    const float* x    = (const float*)d_in[0];
    const int*   ei   = (const int*)  d_in[1];
    const float* ea   = (const float*)d_in[2];
    const int*   batch= (const int*)  d_in[3];
    const float* W1   = (const float*)d_in[4];
    const float* We1  = (const float*)d_in[5];
    const float* as1  = (const float*)d_in[6];
    const float* ad1  = (const float*)d_in[7];
    const float* ae1  = (const float*)d_in[8];
    const float* b1   = (const float*)d_in[9];
    const float* g1   = (const float*)d_in[10];
    const float* be1  = (const float*)d_in[11];
    const float* m1   = (const float*)d_in[12];
    const float* v1   = (const float*)d_in[13];
    const float* W2   = (const float*)d_in[14];
    const float* We2  = (const float*)d_in[15];
    const float* as2  = (const float*)d_in[16];
    const float* ad2  = (const float*)d_in[17];
    const float* ae2  = (const float*)d_in[18];
    const float* b2   = (const float*)d_in[19];
    const float* g2   = (const float*)d_in[20];
    const float* be2  = (const float*)d_in[21];
    const float* m2   = (const float*)d_in[22];
    const float* v2   = (const float*)d_in[23];
    const float* fcW  = (const float*)d_in[24];
    const float* fcb  = (const float*)d_in[25];
    float* out = (float*)d_out;

    char* ws = (char*)d_ws;
    size_t off = 0;
    auto alloc = [&](size_t bytes) -> void* {
        void* p = ws + off;
        off += (bytes + 255) & ~(size_t)255;
        return p;
    };
    int*   deg     = (int*)  alloc((size_t)N_NODES * 4);
    float* easum   = (float*)alloc((size_t)N_NODES * 4);
    int*   row_off = (int*)  alloc((size_t)N_NODES * 4);
    int*   cursor  = (int*)  alloc((size_t)N_NODES * 4);
    int*   adj_src = (int*)  alloc((size_t)N_EDGES * 4);
    float* adj_ea  = (float*)alloc((size_t)N_EDGES * 4);
    float* al_s1   = (float*)alloc((size_t)N_NODES * HEADS * 4);
    float* al_d1   = (float*)alloc((size_t)N_NODES * HEADS * 4);
    float* al_s2   = (float*)alloc((size_t)N_NODES * 4);
    float* al_d2   = (float*)alloc((size_t)N_NODES * 4);
    float* wedot   = (float*)alloc(16 * 4);
    int*   partials= (int*)  alloc(64 * 4);
    int*   poff    = (int*)  alloc(64 * 4);
    float* pool    = (float*)alloc((size_t)G_GRAPHS * HID * 4);
    int*   pcnt    = (int*)  alloc((size_t)G_GRAPHS * 4);
    float* h1      = (float*)alloc((size_t)N_NODES * D1 * 4);
    float* h1p     = (float*)alloc((size_t)N_NODES * D1 * 4);
    float* h2      = (float*)alloc((size_t)N_NODES * HID * 4);
    (void)ws_size; (void)in_sizes; (void)n_in; (void)out_size;

    hipMemsetAsync(deg,   0, (size_t)N_NODES * 4, stream);
    hipMemsetAsync(easum, 0, (size_t)N_NODES * 4, stream);
    hipMemsetAsync(pool,  0, (size_t)G_GRAPHS * HID * 4, stream);
    hipMemsetAsync(pcnt,  0, (size_t)G_GRAPHS * 4, stream);

    k_deg<<<(N_EDGES + 255) / 256, 256, 0, stream>>>(ei, ea, deg, easum);
    k_partial<<<NCHUNK, 256, 0, stream>>>(deg, partials);
    k_scanp<<<1, 64, 0, stream>>>(partials, poff);
    k_scanc<<<NCHUNK, 256, 0, stream>>>(deg, poff, row_off, cursor);
    k_fill<<<(N_EDGES + 255) / 256, 256, 0, stream>>>(ei, ea, cursor, adj_src, adj_ea);
    k_prep<<<1, 64, 0, stream>>>(We1, ae1, We2, ae2, wedot);

    k_gemm1<<<N_NODES / 16, 256, 0, stream>>>(x, W1, h1);
    k_alpha1<<<N_NODES, 256, 0, stream>>>(h1, as1, ad1, al_s1, al_d1);
    k_aggr1<<<N_NODES, 256, 0, stream>>>(row_off, deg, adj_src, adj_ea, easum, h1,
                                         al_s1, al_d1, wedot, b1, g1, be1, m1, v1, h1p);

    k_gemm2<<<(N_NODES * HID + 255) / 256, 256, 0, stream>>>(h1p, W2, h2);
    k_alpha2<<<(N_NODES * HID + 255) / 256, 256, 0, stream>>>(h2, as2, ad2, al_s2, al_d2);
    k_aggr2<<<(N_NODES + 7) / 8, 256, 0, stream>>>(row_off, deg, adj_src, adj_ea, easum,
                                                   h2, al_s2, al_d2, wedot, b2, g2, be2,
                                                   m2, v2, batch, pool, pcnt);
    k_fc<<<2, 256, 0, stream>>>(pool, pcnt, fcW, fcb, out);
}

// Round 2
// 407.270 us; speedup vs baseline: 1.3369x; 1.3369x over previous
//
#include <hip/hip_runtime.h>
#include <hip/hip_bf16.h>

#define N_NODES 50000
#define N_EDGES 600000
#define F_IN    92
#define HID     32
#define HEADS   8
#define D1      256
#define G_GRAPHS 512
#define EPSV    1e-5f
#define NCHUNK  49   // ceil(50000/1024)

typedef unsigned short ushortv8 __attribute__((ext_vector_type(8)));

__device__ __forceinline__ float bf2f(unsigned short u) {
    return __uint_as_float(((unsigned)u) << 16);
}
__device__ __forceinline__ unsigned short f2bf(float f) {
    unsigned u = __float_as_uint(f);
    return (unsigned short)((u + 0x7FFFu + ((u >> 16) & 1u)) >> 16);  // RNE
}

// ---------------- CSR build ----------------

__global__ void k_deg(const int* __restrict__ ei, const float* __restrict__ ea,
                      int* __restrict__ deg, float* __restrict__ easum) {
    int e = blockIdx.x * 256 + threadIdx.x;
    if (e < N_EDGES) {
        int d = ei[N_EDGES + e];
        atomicAdd(&deg[d], 1);
        atomicAdd(&easum[d], ea[e]);
    }
}

__global__ void k_partial(const int* __restrict__ deg, int* __restrict__ partials) {
    int b = blockIdx.x;
    int s = 0;
    for (int j = 0; j < 4; ++j) {
        int i = b * 1024 + j * 256 + threadIdx.x;
        if (i < N_NODES) s += deg[i];
    }
    for (int off = 32; off; off >>= 1) s += __shfl_down(s, off, 64);
    __shared__ int sm[4];
    if ((threadIdx.x & 63) == 0) sm[threadIdx.x >> 6] = s;
    __syncthreads();
    if (threadIdx.x == 0) partials[b] = sm[0] + sm[1] + sm[2] + sm[3];
}

__global__ void k_scanp(const int* __restrict__ partials, int* __restrict__ poff) {
    if (threadIdx.x == 0 && blockIdx.x == 0) {
        int acc = 0;
        for (int b = 0; b < NCHUNK; ++b) { poff[b] = acc; acc += partials[b]; }
    }
}

__global__ void k_scanc(const int* __restrict__ deg, const int* __restrict__ poff,
                        int* __restrict__ row_off, int* __restrict__ cursor) {
    int b = blockIdx.x;
    int t = threadIdx.x;
    int base_i = b * 1024 + t * 4;
    int v[4]; int s = 0;
    #pragma unroll
    for (int j = 0; j < 4; ++j) {
        int i = base_i + j;
        v[j] = (i < N_NODES) ? deg[i] : 0;
        s += v[j];
    }
    __shared__ int sm[256];
    sm[t] = s;
    __syncthreads();
    int val = s;
    for (int off = 1; off < 256; off <<= 1) {
        int add = (t >= off) ? sm[t - off] : 0;
        __syncthreads();
        val += add;
        sm[t] = val;
        __syncthreads();
    }
    int base = poff[b] + (val - s);   // exclusive prefix
    #pragma unroll
    for (int j = 0; j < 4; ++j) {
        int i = base_i + j;
        if (i < N_NODES) { row_off[i] = base; cursor[i] = base; }
        base += v[j];
    }
}

__global__ void k_fill(const int* __restrict__ ei, const float* __restrict__ ea,
                       int* __restrict__ cursor, int* __restrict__ adj_src,
                       float* __restrict__ adj_ea) {
    int e = blockIdx.x * 256 + threadIdx.x;
    if (e < N_EDGES) {
        int d = ei[N_EDGES + e];
        int pos = atomicAdd(&cursor[d], 1);
        adj_src[pos] = ei[e];
        adj_ea[pos] = ea[e];
    }
}

__global__ void k_prep(const float* __restrict__ We1, const float* __restrict__ ae1,
                       const float* __restrict__ We2, const float* __restrict__ ae2,
                       float* __restrict__ wedot) {
    int t = threadIdx.x;
    if (t < HEADS) {
        float a = 0.f;
        for (int c = 0; c < HID; ++c) a += We1[t * HID + c] * ae1[t * HID + c];
        wedot[t] = a;
    } else if (t == HEADS) {
        float a = 0.f;
        for (int c = 0; c < HID; ++c) a += We2[c] * ae2[c];
        wedot[HEADS] = a;
    }
}

// ---------------- conv1 ----------------

// x @ W1 -> h1 (bf16). Block: 16 nodes x 256 cols.
__global__ __launch_bounds__(256) void k_gemm1(const float* __restrict__ x,
                                               const float* __restrict__ W1,
                                               unsigned short* __restrict__ h1) {
    __shared__ float xs[16 * F_IN];
    int n0 = blockIdx.x * 16;
    for (int i = threadIdx.x; i < 16 * F_IN; i += 256)
        xs[i] = x[(size_t)n0 * F_IN + i];
    __syncthreads();
    int col = threadIdx.x;
    float acc[16];
    #pragma unroll
    for (int r = 0; r < 16; ++r) acc[r] = 0.f;
    for (int k = 0; k < F_IN; ++k) {
        float w = W1[k * D1 + col];
        #pragma unroll
        for (int r = 0; r < 16; ++r) acc[r] += xs[r * F_IN + k] * w;
    }
    #pragma unroll
    for (int r = 0; r < 16; ++r)
        h1[(size_t)(n0 + r) * D1 + col] = f2bf(acc[r]);
}

// per-node attention logits from bf16 h1; 1 wave per node, 4 nodes/block
__global__ __launch_bounds__(256) void k_alpha1(const unsigned short* __restrict__ h1,
                                                const float* __restrict__ as1,
                                                const float* __restrict__ ad1,
                                                float* __restrict__ al_s,
                                                float* __restrict__ al_d) {
    int wid = threadIdx.x >> 6, l = threadIdx.x & 63;
    int n = blockIdx.x * 4 + wid;
    if (n >= N_NODES) return;
    ushort4 p = *(const ushort4*)(h1 + (size_t)n * D1 + l * 4);
    int c = l * 4;
    float v0 = bf2f(p.x), v1 = bf2f(p.y), v2 = bf2f(p.z), v3 = bf2f(p.w);
    float vs = v0 * as1[c] + v1 * as1[c + 1] + v2 * as1[c + 2] + v3 * as1[c + 3];
    float vd = v0 * ad1[c] + v1 * ad1[c + 1] + v2 * ad1[c + 2] + v3 * ad1[c + 3];
    #pragma unroll
    for (int off = 1; off < 8; off <<= 1) {
        vs += __shfl_xor(vs, off, 64);
        vd += __shfl_xor(vd, off, 64);
    }
    if ((l & 7) == 0) {
        al_s[n * HEADS + (l >> 3)] = vs;
        al_d[n * HEADS + (l >> 3)] = vd;
    }
}

// aggregation conv1: 1 wave per node, lane l handles channels 4l..4l+3
__global__ __launch_bounds__(256) void k_aggr1(
        const int* __restrict__ row_off, const int* __restrict__ deg,
        const int* __restrict__ adj_src, const float* __restrict__ adj_ea,
        const float* __restrict__ easum, const unsigned short* __restrict__ h1,
        const float* __restrict__ al_s, const float* __restrict__ al_d,
        const float* __restrict__ wedot,
        const float* __restrict__ b1, const float* __restrict__ g1,
        const float* __restrict__ be1, const float* __restrict__ m1,
        const float* __restrict__ v1, unsigned short* __restrict__ h1p) {
    int wid = threadIdx.x >> 6, l = threadIdx.x & 63;
    int n = blockIdx.x * 4 + wid;
    if (n >= N_NODES) return;
    int h = l >> 3;
    float wd = wedot[h];
    float dn = al_d[n * HEADS + h];
    int r0 = row_off[n], cnt = deg[n];
    float a0 = 0.f, a1 = 0.f, a2 = 0.f, a3 = 0.f, den = 0.f;
    for (int base = 0; base < cnt; base += 64) {
        int m = cnt - base; if (m > 64) m = 64;
        int sl = 0; float el = 0.f;
        if (l < m) {
            sl = adj_src[r0 + base + l];
            el = adj_ea[r0 + base + l];
        }
        for (int i = 0; i < m; ++i) {
            int s = __shfl(sl, i, 64);
            float eav = __shfl(el, i, 64);
            float a = al_s[s * HEADS + h] + dn + eav * wd;
            a = a > 0.f ? a : 0.2f * a;
            float w = __expf(a);
            den += w;
            ushort4 p = *(const ushort4*)(h1 + (size_t)s * D1 + l * 4);
            a0 += w * bf2f(p.x); a1 += w * bf2f(p.y);
            a2 += w * bf2f(p.z); a3 += w * bf2f(p.w);
        }
    }
    {   // self loop, attr = mean of incoming (0 if none)
        float la = easum[n] / (float)(cnt > 0 ? cnt : 1);
        float a = al_s[n * HEADS + h] + dn + la * wd;
        a = a > 0.f ? a : 0.2f * a;
        float w = __expf(a);
        den += w;
        ushort4 p = *(const ushort4*)(h1 + (size_t)n * D1 + l * 4);
        a0 += w * bf2f(p.x); a1 += w * bf2f(p.y);
        a2 += w * bf2f(p.z); a3 += w * bf2f(p.w);
    }
    float inv = 1.f / den;
    int c = l * 4;
    ushort4 o;
    float acc[4] = {a0, a1, a2, a3};
    unsigned short* po = (unsigned short*)&o;
    #pragma unroll
    for (int j = 0; j < 4; ++j) {
        float ov = acc[j] * inv + b1[c + j];
        float sc = g1[c + j] * __frsqrt_rn(v1[c + j] + EPSV);
        float y = (ov - m1[c + j]) * sc + be1[c + j];
        po[j] = f2bf(y > 0.f ? y : 0.f);
    }
    *(ushort4*)(h1p + (size_t)n * D1 + c) = o;
}

// ---------------- conv2 ----------------

__global__ void k_gemm2(const unsigned short* __restrict__ h1p,
                        const float* __restrict__ W2, float* __restrict__ h2) {
    int gid = blockIdx.x * 256 + threadIdx.x;
    if (gid >= N_NODES * HID) return;
    int n = gid >> 5, c = gid & 31;
    float acc = 0.f;
    const ushortv8* hp = (const ushortv8*)(h1p + (size_t)n * D1);
    #pragma unroll 4
    for (int k8 = 0; k8 < 32; ++k8) {
        ushortv8 hv = hp[k8];
        #pragma unroll
        for (int j = 0; j < 8; ++j)
            acc += bf2f(hv[j]) * W2[(k8 * 8 + j) * HID + c];
    }
    h2[gid] = acc;
}

__global__ void k_alpha2(const float* __restrict__ h2, const float* __restrict__ as2,
                         const float* __restrict__ ad2, float* __restrict__ al_s2,
                         float* __restrict__ al_d2) {
    int gid = blockIdx.x * 256 + threadIdx.x;
    int n = gid >> 5, c = gid & 31;
    if (n >= N_NODES) return;
    float v = h2[gid];
    float vs = v * as2[c];
    float vd = v * ad2[c];
    #pragma unroll
    for (int off = 16; off; off >>= 1) {
        vs += __shfl_xor(vs, off, 64);
        vd += __shfl_xor(vd, off, 64);
    }
    if (c == 0) { al_s2[n] = vs; al_d2[n] = vd; }
}

__global__ void k_aggr2(
        const int* __restrict__ row_off, const int* __restrict__ deg,
        const int* __restrict__ adj_src, const float* __restrict__ adj_ea,
        const float* __restrict__ easum, const float* __restrict__ h2,
        const float* __restrict__ al_s2, const float* __restrict__ al_d2,
        const float* __restrict__ wedot,
        const float* __restrict__ b2, const float* __restrict__ g2,
        const float* __restrict__ be2, const float* __restrict__ m2,
        const float* __restrict__ v2, const int* __restrict__ batch,
        float* __restrict__ pool, int* __restrict__ pcnt) {
    int t = threadIdx.x;
    int ln = t >> 5, c = t & 31;
    int n = blockIdx.x * 8 + ln;
    if (n >= N_NODES) return;
    float wd = wedot[HEADS];
    float dn = al_d2[n];
    int r0 = row_off[n], cnt = deg[n];
    float acc = 0.f, den = 0.f;
    for (int i = 0; i < cnt; ++i) {
        int s = adj_src[r0 + i];
        float eav = adj_ea[r0 + i];
        float a = al_s2[s] + dn + eav * wd;
        a = a > 0.f ? a : 0.2f * a;
        float w = __expf(a);
        den += w;
        acc += w * h2[(size_t)s * HID + c];
    }
    {
        float la = easum[n] / (float)(cnt > 0 ? cnt : 1);
        float a = al_s2[n] + dn + la * wd;
        a = a > 0.f ? a : 0.2f * a;
        float w = __expf(a);
        den += w;
        acc += w * h2[(size_t)n * HID + c];
    }
    float o = acc / den + b2[c];
    float sc = g2[c] * __frsqrt_rn(v2[c] + EPSV);
    float y = (o - m2[c]) * sc + be2[c];
    y = y > 0.f ? y : 0.f;
    int g = batch[n];
    atomicAdd(&pool[g * HID + c], y);
    if (c == 0) atomicAdd(&pcnt[g], 1);
}

__global__ void k_fc(const float* __restrict__ pool, const int* __restrict__ pcnt,
                     const float* __restrict__ fcW, const float* __restrict__ fcb,
                     float* __restrict__ out) {
    int g = blockIdx.x * 256 + threadIdx.x;
    if (g >= G_GRAPHS) return;
    float cg = (float)(pcnt[g] > 0 ? pcnt[g] : 1);
    float acc = 0.f;
    #pragma unroll
    for (int c = 0; c < HID; ++c) acc += pool[g * HID + c] * fcW[c];
    out[g] = acc / cg + fcb[0];
}

// ---------------- launch ----------------

extern "C" void kernel_launch(void* const* d_in, const int* in_sizes, int n_in,
                              void* d_out, int out_size, void* d_ws, size_t ws_size,
                              hipStream_t stream) {
    const float* x    = (const float*)d_in[0];
    const int*   ei   = (const int*)  d_in[1];
    const float* ea   = (const float*)d_in[2];
    const int*   batch= (const int*)  d_in[3];
    const float* W1   = (const float*)d_in[4];
    const float* We1  = (const float*)d_in[5];
    const float* as1  = (const float*)d_in[6];
    const float* ad1  = (const float*)d_in[7];
    const float* ae1  = (const float*)d_in[8];
    const float* b1   = (const float*)d_in[9];
    const float* g1   = (const float*)d_in[10];
    const float* be1  = (const float*)d_in[11];
    const float* m1   = (const float*)d_in[12];
    const float* v1   = (const float*)d_in[13];
    const float* W2   = (const float*)d_in[14];
    const float* We2  = (const float*)d_in[15];
    const float* as2  = (const float*)d_in[16];
    const float* ad2  = (const float*)d_in[17];
    const float* ae2  = (const float*)d_in[18];
    const float* b2   = (const float*)d_in[19];
    const float* g2   = (const float*)d_in[20];
    const float* be2  = (const float*)d_in[21];
    const float* m2   = (const float*)d_in[22];
    const float* v2   = (const float*)d_in[23];
    const float* fcW  = (const float*)d_in[24];
    const float* fcb  = (const float*)d_in[25];
    float* out = (float*)d_out;

    char* ws = (char*)d_ws;
    size_t off = 0;
    auto alloc = [&](size_t bytes) -> void* {
        void* p = ws + off;
        off += (bytes + 255) & ~(size_t)255;
        return p;
    };
    int*   deg     = (int*)  alloc((size_t)N_NODES * 4);
    float* easum   = (float*)alloc((size_t)N_NODES * 4);
    int*   row_off = (int*)  alloc((size_t)N_NODES * 4);
    int*   cursor  = (int*)  alloc((size_t)N_NODES * 4);
    int*   adj_src = (int*)  alloc((size_t)N_EDGES * 4);
    float* adj_ea  = (float*)alloc((size_t)N_EDGES * 4);
    float* al_s1   = (float*)alloc((size_t)N_NODES * HEADS * 4);
    float* al_d1   = (float*)alloc((size_t)N_NODES * HEADS * 4);
    float* al_s2   = (float*)alloc((size_t)N_NODES * 4);
    float* al_d2   = (float*)alloc((size_t)N_NODES * 4);
    float* wedot   = (float*)alloc(16 * 4);
    int*   partials= (int*)  alloc(64 * 4);
    int*   poff    = (int*)  alloc(64 * 4);
    float* pool    = (float*)alloc((size_t)G_GRAPHS * HID * 4);
    int*   pcnt    = (int*)  alloc((size_t)G_GRAPHS * 4);
    unsigned short* h1  = (unsigned short*)alloc((size_t)N_NODES * D1 * 2);
    unsigned short* h1p = (unsigned short*)alloc((size_t)N_NODES * D1 * 2);
    float* h2      = (float*)alloc((size_t)N_NODES * HID * 4);
    (void)ws_size; (void)in_sizes; (void)n_in; (void)out_size;

    hipMemsetAsync(deg,   0, (size_t)N_NODES * 4, stream);
    hipMemsetAsync(easum, 0, (size_t)N_NODES * 4, stream);
    hipMemsetAsync(pool,  0, (size_t)G_GRAPHS * HID * 4, stream);
    hipMemsetAsync(pcnt,  0, (size_t)G_GRAPHS * 4, stream);

    k_deg<<<(N_EDGES + 255) / 256, 256, 0, stream>>>(ei, ea, deg, easum);
    k_partial<<<NCHUNK, 256, 0, stream>>>(deg, partials);
    k_scanp<<<1, 64, 0, stream>>>(partials, poff);
    k_scanc<<<NCHUNK, 256, 0, stream>>>(deg, poff, row_off, cursor);
    k_fill<<<(N_EDGES + 255) / 256, 256, 0, stream>>>(ei, ea, cursor, adj_src, adj_ea);
    k_prep<<<1, 64, 0, stream>>>(We1, ae1, We2, ae2, wedot);

    k_gemm1<<<N_NODES / 16, 256, 0, stream>>>(x, W1, h1);
    k_alpha1<<<(N_NODES + 3) / 4, 256, 0, stream>>>(h1, as1, ad1, al_s1, al_d1);
    k_aggr1<<<(N_NODES + 3) / 4, 256, 0, stream>>>(row_off, deg, adj_src, adj_ea, easum,
                                                   h1, al_s1, al_d1, wedot, b1, g1, be1,
                                                   m1, v1, h1p);

    k_gemm2<<<(N_NODES * HID + 255) / 256, 256, 0, stream>>>(h1p, W2, h2);
    k_alpha2<<<(N_NODES * HID + 255) / 256, 256, 0, stream>>>(h2, as2, ad2, al_s2, al_d2);
    k_aggr2<<<(N_NODES + 7) / 8, 256, 0, stream>>>(row_off, deg, adj_src, adj_ea, easum,
                                                   h2, al_s2, al_d2, wedot, b2, g2, be2,
                                                   m2, v2, batch, pool, pcnt);
    k_fc<<<2, 256, 0, stream>>>(pool, pcnt, fcW, fcb, out);
}

// Round 3
// 362.812 us; speedup vs baseline: 1.5007x; 1.1225x over previous
//
#include <hip/hip_runtime.h>
#include <hip/hip_bf16.h>

#define N_NODES 50000
#define N_EDGES 600000
#define F_IN    92
#define HID     32
#define HEADS   8
#define D1      256
#define G_GRAPHS 512
#define EPSV    1e-5f
#define NCHUNK  49   // ceil(50000/1024)

typedef unsigned short ushortv8 __attribute__((ext_vector_type(8)));

__device__ __forceinline__ float bf2f(unsigned short u) {
    return __uint_as_float(((unsigned)u) << 16);
}
__device__ __forceinline__ unsigned short f2bf(float f) {
    unsigned u = __float_as_uint(f);
    return (unsigned short)((u + 0x7FFFu + ((u >> 16) & 1u)) >> 16);  // RNE
}

// ---------------- CSR build ----------------

__global__ void k_deg(const int* __restrict__ ei, const float* __restrict__ ea,
                      int* __restrict__ deg, float* __restrict__ easum) {
    int e = blockIdx.x * 256 + threadIdx.x;
    if (e < N_EDGES) {
        int d = ei[N_EDGES + e];
        atomicAdd(&deg[d], 1);
        atomicAdd(&easum[d], ea[e]);
    }
}

__global__ void k_partial(const int* __restrict__ deg, int* __restrict__ partials) {
    int b = blockIdx.x;
    int s = 0;
    for (int j = 0; j < 4; ++j) {
        int i = b * 1024 + j * 256 + threadIdx.x;
        if (i < N_NODES) s += deg[i];
    }
    for (int off = 32; off; off >>= 1) s += __shfl_down(s, off, 64);
    __shared__ int sm[4];
    if ((threadIdx.x & 63) == 0) sm[threadIdx.x >> 6] = s;
    __syncthreads();
    if (threadIdx.x == 0) partials[b] = sm[0] + sm[1] + sm[2] + sm[3];
}

__global__ void k_scanp(const int* __restrict__ partials, int* __restrict__ poff) {
    if (threadIdx.x == 0 && blockIdx.x == 0) {
        int acc = 0;
        for (int b = 0; b < NCHUNK; ++b) { poff[b] = acc; acc += partials[b]; }
    }
}

__global__ void k_scanc(const int* __restrict__ deg, const int* __restrict__ poff,
                        int* __restrict__ row_off, int* __restrict__ cursor) {
    int b = blockIdx.x;
    int t = threadIdx.x;
    int base_i = b * 1024 + t * 4;
    int v[4]; int s = 0;
    #pragma unroll
    for (int j = 0; j < 4; ++j) {
        int i = base_i + j;
        v[j] = (i < N_NODES) ? deg[i] : 0;
        s += v[j];
    }
    __shared__ int sm[256];
    sm[t] = s;
    __syncthreads();
    int val = s;
    for (int off = 1; off < 256; off <<= 1) {
        int add = (t >= off) ? sm[t - off] : 0;
        __syncthreads();
        val += add;
        sm[t] = val;
        __syncthreads();
    }
    int base = poff[b] + (val - s);   // exclusive prefix
    #pragma unroll
    for (int j = 0; j < 4; ++j) {
        int i = base_i + j;
        if (i < N_NODES) { row_off[i] = base; cursor[i] = base; }
        base += v[j];
    }
}

__global__ void k_fill(const int* __restrict__ ei, const float* __restrict__ ea,
                       int* __restrict__ cursor, int* __restrict__ adj_src,
                       float* __restrict__ adj_ea) {
    int e = blockIdx.x * 256 + threadIdx.x;
    if (e < N_EDGES) {
        int d = ei[N_EDGES + e];
        int pos = atomicAdd(&cursor[d], 1);
        adj_src[pos] = ei[e];
        adj_ea[pos] = ea[e];
    }
}

__global__ void k_prep(const float* __restrict__ We1, const float* __restrict__ ae1,
                       const float* __restrict__ We2, const float* __restrict__ ae2,
                       float* __restrict__ wedot) {
    int t = threadIdx.x;
    if (t < HEADS) {
        float a = 0.f;
        for (int c = 0; c < HID; ++c) a += We1[t * HID + c] * ae1[t * HID + c];
        wedot[t] = a;
    } else if (t == HEADS) {
        float a = 0.f;
        for (int c = 0; c < HID; ++c) a += We2[c] * ae2[c];
        wedot[HEADS] = a;
    }
}

// ---------------- conv1 ----------------

// x @ W1 -> h1 (bf16). Block: 16 nodes x 256 cols.
__global__ __launch_bounds__(256) void k_gemm1(const float* __restrict__ x,
                                               const float* __restrict__ W1,
                                               unsigned short* __restrict__ h1) {
    __shared__ float xs[16 * F_IN];
    int n0 = blockIdx.x * 16;
    for (int i = threadIdx.x; i < 16 * F_IN; i += 256)
        xs[i] = x[(size_t)n0 * F_IN + i];
    __syncthreads();
    int col = threadIdx.x;
    float acc[16];
    #pragma unroll
    for (int r = 0; r < 16; ++r) acc[r] = 0.f;
    for (int k = 0; k < F_IN; ++k) {
        float w = W1[k * D1 + col];
        #pragma unroll
        for (int r = 0; r < 16; ++r) acc[r] += xs[r * F_IN + k] * w;
    }
    #pragma unroll
    for (int r = 0; r < 16; ++r)
        h1[(size_t)(n0 + r) * D1 + col] = f2bf(acc[r]);
}

// per-node attention logits from bf16 h1; 1 wave per node, 4 nodes/block
__global__ __launch_bounds__(256) void k_alpha1(const unsigned short* __restrict__ h1,
                                                const float* __restrict__ as1,
                                                const float* __restrict__ ad1,
                                                float* __restrict__ al_s,
                                                float* __restrict__ al_d) {
    int wid = threadIdx.x >> 6, l = threadIdx.x & 63;
    int n = blockIdx.x * 4 + wid;
    if (n >= N_NODES) return;
    ushort4 p = *(const ushort4*)(h1 + (size_t)n * D1 + l * 4);
    int c = l * 4;
    float v0 = bf2f(p.x), v1 = bf2f(p.y), v2 = bf2f(p.z), v3 = bf2f(p.w);
    float vs = v0 * as1[c] + v1 * as1[c + 1] + v2 * as1[c + 2] + v3 * as1[c + 3];
    float vd = v0 * ad1[c] + v1 * ad1[c + 1] + v2 * ad1[c + 2] + v3 * ad1[c + 3];
    #pragma unroll
    for (int off = 1; off < 8; off <<= 1) {
        vs += __shfl_xor(vs, off, 64);
        vd += __shfl_xor(vd, off, 64);
    }
    if ((l & 7) == 0) {
        al_s[n * HEADS + (l >> 3)] = vs;
        al_d[n * HEADS + (l >> 3)] = vd;
    }
}

// aggregation conv1: 1 wave per node, lane l handles channels 4l..4l+3
__global__ __launch_bounds__(256) void k_aggr1(
        const int* __restrict__ row_off, const int* __restrict__ deg,
        const int* __restrict__ adj_src, const float* __restrict__ adj_ea,
        const float* __restrict__ easum, const unsigned short* __restrict__ h1,
        const float* __restrict__ al_s, const float* __restrict__ al_d,
        const float* __restrict__ wedot,
        const float* __restrict__ b1, const float* __restrict__ g1,
        const float* __restrict__ be1, const float* __restrict__ m1,
        const float* __restrict__ v1, unsigned short* __restrict__ h1p) {
    int wid = threadIdx.x >> 6, l = threadIdx.x & 63;
    int n = blockIdx.x * 4 + wid;
    if (n >= N_NODES) return;
    int h = l >> 3;
    float wd = wedot[h];
    float dn = al_d[n * HEADS + h];
    int r0 = row_off[n], cnt = deg[n];
    float a0 = 0.f, a1 = 0.f, a2 = 0.f, a3 = 0.f, den = 0.f;
    for (int base = 0; base < cnt; base += 64) {
        int m = cnt - base; if (m > 64) m = 64;
        int sl = 0; float el = 0.f;
        if (l < m) {
            sl = adj_src[r0 + base + l];
            el = adj_ea[r0 + base + l];
        }
        for (int i = 0; i < m; ++i) {
            int s = __shfl(sl, i, 64);
            float eav = __shfl(el, i, 64);
            float a = al_s[s * HEADS + h] + dn + eav * wd;
            a = a > 0.f ? a : 0.2f * a;
            float w = __expf(a);
            den += w;
            ushort4 p = *(const ushort4*)(h1 + (size_t)s * D1 + l * 4);
            a0 += w * bf2f(p.x); a1 += w * bf2f(p.y);
            a2 += w * bf2f(p.z); a3 += w * bf2f(p.w);
        }
    }
    {   // self loop, attr = mean of incoming (0 if none)
        float la = easum[n] / (float)(cnt > 0 ? cnt : 1);
        float a = al_s[n * HEADS + h] + dn + la * wd;
        a = a > 0.f ? a : 0.2f * a;
        float w = __expf(a);
        den += w;
        ushort4 p = *(const ushort4*)(h1 + (size_t)n * D1 + l * 4);
        a0 += w * bf2f(p.x); a1 += w * bf2f(p.y);
        a2 += w * bf2f(p.z); a3 += w * bf2f(p.w);
    }
    float inv = 1.f / den;
    int c = l * 4;
    ushort4 o;
    float acc[4] = {a0, a1, a2, a3};
    unsigned short* po = (unsigned short*)&o;
    #pragma unroll
    for (int j = 0; j < 4; ++j) {
        float ov = acc[j] * inv + b1[c + j];
        float sc = g1[c + j] * __frsqrt_rn(v1[c + j] + EPSV);
        float y = (ov - m1[c + j]) * sc + be1[c + j];
        po[j] = f2bf(y > 0.f ? y : 0.f);
    }
    *(ushort4*)(h1p + (size_t)n * D1 + c) = o;
}

// ---------------- conv2 ----------------

__global__ void k_gemm2(const unsigned short* __restrict__ h1p,
                        const float* __restrict__ W2, float* __restrict__ h2) {
    int gid = blockIdx.x * 256 + threadIdx.x;
    if (gid >= N_NODES * HID) return;
    int n = gid >> 5, c = gid & 31;
    float acc = 0.f;
    const ushortv8* hp = (const ushortv8*)(h1p + (size_t)n * D1);
    #pragma unroll 4
    for (int k8 = 0; k8 < 32; ++k8) {
        ushortv8 hv = hp[k8];
        #pragma unroll
        for (int j = 0; j < 8; ++j)
            acc += bf2f(hv[j]) * W2[(k8 * 8 + j) * HID + c];
    }
    h2[gid] = acc;
}

__global__ void k_alpha2(const float* __restrict__ h2, const float* __restrict__ as2,
                         const float* __restrict__ ad2, float* __restrict__ al_s2,
                         float* __restrict__ al_d2) {
    int gid = blockIdx.x * 256 + threadIdx.x;
    int n = gid >> 5, c = gid & 31;
    if (n >= N_NODES) return;
    float v = h2[gid];
    float vs = v * as2[c];
    float vd = v * ad2[c];
    #pragma unroll
    for (int off = 16; off; off >>= 1) {
        vs += __shfl_xor(vs, off, 64);
        vd += __shfl_xor(vd, off, 64);
    }
    if (c == 0) { al_s2[n] = vs; al_d2[n] = vd; }
}

// aggregation conv2: 1 wave per node, 2 edges/iter (half-waves), no atomics.
__global__ __launch_bounds__(256) void k_aggr2(
        const int* __restrict__ row_off, const int* __restrict__ deg,
        const int* __restrict__ adj_src, const float* __restrict__ adj_ea,
        const float* __restrict__ easum, const float* __restrict__ h2,
        const float* __restrict__ al_s2, const float* __restrict__ al_d2,
        const float* __restrict__ wedot,
        const float* __restrict__ b2, const float* __restrict__ g2,
        const float* __restrict__ be2, const float* __restrict__ m2,
        const float* __restrict__ v2, float* __restrict__ h2p) {
    int wid = threadIdx.x >> 6, l = threadIdx.x & 63;
    int n = blockIdx.x * 4 + wid;
    if (n >= N_NODES) return;
    int c = l & 31, half = l >> 5;
    float wd = wedot[HEADS];
    float dn = al_d2[n];
    int r0 = row_off[n], cnt = deg[n];
    float acc = 0.f, den = 0.f;
    for (int base = 0; base < cnt; base += 64) {
        int m = cnt - base; if (m > 64) m = 64;
        int sl = 0; float el = 0.f;
        if (l < m) {
            sl = adj_src[r0 + base + l];
            el = adj_ea[r0 + base + l];
        }
        for (int i = 0; i < m; i += 2) {
            int j = i + half;
            bool ok = j < m;
            int jj = ok ? j : 0;
            int s = __shfl(sl, jj, 64);
            float eav = __shfl(el, jj, 64);
            if (ok) {
                float a = al_s2[s] + dn + eav * wd;
                a = a > 0.f ? a : 0.2f * a;
                float w = __expf(a);
                den += w;
                acc += w * h2[(size_t)s * HID + c];
            }
        }
    }
    // merge the two half-wave partial sums
    acc += __shfl_xor(acc, 32, 64);
    den += __shfl_xor(den, 32, 64);
    {   // self loop (each lane adds exactly once)
        float la = easum[n] / (float)(cnt > 0 ? cnt : 1);
        float a = al_s2[n] + dn + la * wd;
        a = a > 0.f ? a : 0.2f * a;
        float w = __expf(a);
        den += w;
        acc += w * h2[(size_t)n * HID + c];
    }
    float o = acc / den + b2[c];
    float sc = g2[c] * __frsqrt_rn(v2[c] + EPSV);
    float y = (o - m2[c]) * sc + be2[c];
    y = y > 0.f ? y : 0.f;
    if (half == 0) h2p[(size_t)n * HID + c] = y;
}

// pool (mean over sorted batch segments) + fc, one block per graph
__global__ __launch_bounds__(64) void k_poolfc(const float* __restrict__ h2p,
                                               const int* __restrict__ batch,
                                               const float* __restrict__ fcW,
                                               const float* __restrict__ fcb,
                                               float* __restrict__ out) {
    int g = blockIdx.x;
    int l = threadIdx.x;
    auto lb = [&](int key) {
        int lo = 0, hi = N_NODES;
        while (lo < hi) {
            int mid = (lo + hi) >> 1;
            if (batch[mid] < key) lo = mid + 1; else hi = mid;
        }
        return lo;
    };
    int s0 = lb(g), s1 = lb(g + 1);
    int c = l & 31, half = l >> 5;
    float acc = 0.f;
    for (int r = s0 + half; r < s1; r += 2)
        acc += h2p[(size_t)r * HID + c];
    acc += __shfl_xor(acc, 32, 64);
    int cn = s1 - s0;
    float mean = acc / (float)(cn > 0 ? cn : 1);
    float p = mean * fcW[c];
    #pragma unroll
    for (int off = 1; off < 32; off <<= 1) p += __shfl_xor(p, off, 64);
    if (l == 0) out[g] = p + fcb[0];
}

// ---------------- launch ----------------

extern "C" void kernel_launch(void* const* d_in, const int* in_sizes, int n_in,
                              void* d_out, int out_size, void* d_ws, size_t ws_size,
                              hipStream_t stream) {
    const float* x    = (const float*)d_in[0];
    const int*   ei   = (const int*)  d_in[1];
    const float* ea   = (const float*)d_in[2];
    const int*   batch= (const int*)  d_in[3];
    const float* W1   = (const float*)d_in[4];
    const float* We1  = (const float*)d_in[5];
    const float* as1  = (const float*)d_in[6];
    const float* ad1  = (const float*)d_in[7];
    const float* ae1  = (const float*)d_in[8];
    const float* b1   = (const float*)d_in[9];
    const float* g1   = (const float*)d_in[10];
    const float* be1  = (const float*)d_in[11];
    const float* m1   = (const float*)d_in[12];
    const float* v1   = (const float*)d_in[13];
    const float* W2   = (const float*)d_in[14];
    const float* We2  = (const float*)d_in[15];
    const float* as2  = (const float*)d_in[16];
    const float* ad2  = (const float*)d_in[17];
    const float* ae2  = (const float*)d_in[18];
    const float* b2   = (const float*)d_in[19];
    const float* g2   = (const float*)d_in[20];
    const float* be2  = (const float*)d_in[21];
    const float* m2   = (const float*)d_in[22];
    const float* v2   = (const float*)d_in[23];
    const float* fcW  = (const float*)d_in[24];
    const float* fcb  = (const float*)d_in[25];
    float* out = (float*)d_out;

    char* ws = (char*)d_ws;
    size_t off = 0;
    auto alloc = [&](size_t bytes) -> void* {
        void* p = ws + off;
        off += (bytes + 255) & ~(size_t)255;
        return p;
    };
    int*   deg     = (int*)  alloc((size_t)N_NODES * 4);
    float* easum   = (float*)alloc((size_t)N_NODES * 4);
    int*   row_off = (int*)  alloc((size_t)N_NODES * 4);
    int*   cursor  = (int*)  alloc((size_t)N_NODES * 4);
    int*   adj_src = (int*)  alloc((size_t)N_EDGES * 4);
    float* adj_ea  = (float*)alloc((size_t)N_EDGES * 4);
    float* al_s1   = (float*)alloc((size_t)N_NODES * HEADS * 4);
    float* al_d1   = (float*)alloc((size_t)N_NODES * HEADS * 4);
    float* al_s2   = (float*)alloc((size_t)N_NODES * 4);
    float* al_d2   = (float*)alloc((size_t)N_NODES * 4);
    float* wedot   = (float*)alloc(16 * 4);
    int*   partials= (int*)  alloc(64 * 4);
    int*   poff    = (int*)  alloc(64 * 4);
    unsigned short* h1  = (unsigned short*)alloc((size_t)N_NODES * D1 * 2);
    unsigned short* h1p = (unsigned short*)alloc((size_t)N_NODES * D1 * 2);
    float* h2      = (float*)alloc((size_t)N_NODES * HID * 4);
    float* h2p     = (float*)alloc((size_t)N_NODES * HID * 4);
    (void)ws_size; (void)in_sizes; (void)n_in; (void)out_size;

    hipMemsetAsync(deg,   0, (size_t)N_NODES * 4, stream);
    hipMemsetAsync(easum, 0, (size_t)N_NODES * 4, stream);

    k_deg<<<(N_EDGES + 255) / 256, 256, 0, stream>>>(ei, ea, deg, easum);
    k_partial<<<NCHUNK, 256, 0, stream>>>(deg, partials);
    k_scanp<<<1, 64, 0, stream>>>(partials, poff);
    k_scanc<<<NCHUNK, 256, 0, stream>>>(deg, poff, row_off, cursor);
    k_fill<<<(N_EDGES + 255) / 256, 256, 0, stream>>>(ei, ea, cursor, adj_src, adj_ea);
    k_prep<<<1, 64, 0, stream>>>(We1, ae1, We2, ae2, wedot);

    k_gemm1<<<N_NODES / 16, 256, 0, stream>>>(x, W1, h1);
    k_alpha1<<<(N_NODES + 3) / 4, 256, 0, stream>>>(h1, as1, ad1, al_s1, al_d1);
    k_aggr1<<<(N_NODES + 3) / 4, 256, 0, stream>>>(row_off, deg, adj_src, adj_ea, easum,
                                                   h1, al_s1, al_d1, wedot, b1, g1, be1,
                                                   m1, v1, h1p);

    k_gemm2<<<(N_NODES * HID + 255) / 256, 256, 0, stream>>>(h1p, W2, h2);
    k_alpha2<<<(N_NODES * HID + 255) / 256, 256, 0, stream>>>(h2, as2, ad2, al_s2, al_d2);
    k_aggr2<<<(N_NODES + 3) / 4, 256, 0, stream>>>(row_off, deg, adj_src, adj_ea, easum,
                                                   h2, al_s2, al_d2, wedot, b2, g2, be2,
                                                   m2, v2, h2p);
    k_poolfc<<<G_GRAPHS, 64, 0, stream>>>(h2p, batch, fcW, fcb, out);
}

// Round 4
// 307.742 us; speedup vs baseline: 1.7692x; 1.1789x over previous
//
#include <hip/hip_runtime.h>
#include <hip/hip_bf16.h>

#define N_NODES 50000
#define N_EDGES 600000
#define F_IN    92
#define HID     32
#define HEADS   8
#define D1      256
#define G_GRAPHS 512
#define EPSV    1e-5f
#define NCHUNK  49   // ceil(50000/1024)

typedef unsigned short ushortv8 __attribute__((ext_vector_type(8)));
using short8 = __attribute__((ext_vector_type(8))) short;
using f32x4  = __attribute__((ext_vector_type(4))) float;

__device__ __forceinline__ float bf2f(unsigned short u) {
    return __uint_as_float(((unsigned)u) << 16);
}
__device__ __forceinline__ unsigned short f2bf(float f) {
    unsigned u = __float_as_uint(f);
    return (unsigned short)((u + 0x7FFFu + ((u >> 16) & 1u)) >> 16);  // RNE
}

// ---------------- CSR build ----------------

__global__ void k_deg(const int* __restrict__ ei, const float* __restrict__ ea,
                      int* __restrict__ deg, float* __restrict__ easum) {
    int e = blockIdx.x * 256 + threadIdx.x;
    if (e < N_EDGES) {
        int d = ei[N_EDGES + e];
        atomicAdd(&deg[d], 1);
        atomicAdd(&easum[d], ea[e]);
    }
}

__global__ void k_partial(const int* __restrict__ deg, int* __restrict__ partials) {
    int b = blockIdx.x;
    int s = 0;
    for (int j = 0; j < 4; ++j) {
        int i = b * 1024 + j * 256 + threadIdx.x;
        if (i < N_NODES) s += deg[i];
    }
    for (int off = 32; off; off >>= 1) s += __shfl_down(s, off, 64);
    __shared__ int sm[4];
    if ((threadIdx.x & 63) == 0) sm[threadIdx.x >> 6] = s;
    __syncthreads();
    if (threadIdx.x == 0) partials[b] = sm[0] + sm[1] + sm[2] + sm[3];
}

__global__ void k_scanp(const int* __restrict__ partials, int* __restrict__ poff) {
    if (threadIdx.x == 0 && blockIdx.x == 0) {
        int acc = 0;
        for (int b = 0; b < NCHUNK; ++b) { poff[b] = acc; acc += partials[b]; }
    }
}

__global__ void k_scanc(const int* __restrict__ deg, const int* __restrict__ poff,
                        int* __restrict__ row_off, int* __restrict__ cursor) {
    int b = blockIdx.x;
    int t = threadIdx.x;
    int base_i = b * 1024 + t * 4;
    int v[4]; int s = 0;
    #pragma unroll
    for (int j = 0; j < 4; ++j) {
        int i = base_i + j;
        v[j] = (i < N_NODES) ? deg[i] : 0;
        s += v[j];
    }
    __shared__ int sm[256];
    sm[t] = s;
    __syncthreads();
    int val = s;
    for (int off = 1; off < 256; off <<= 1) {
        int add = (t >= off) ? sm[t - off] : 0;
        __syncthreads();
        val += add;
        sm[t] = val;
        __syncthreads();
    }
    int base = poff[b] + (val - s);   // exclusive prefix
    #pragma unroll
    for (int j = 0; j < 4; ++j) {
        int i = base_i + j;
        if (i < N_NODES) { row_off[i] = base; cursor[i] = base; }
        base += v[j];
    }
}

__global__ void k_fill(const int* __restrict__ ei, const float* __restrict__ ea,
                       int* __restrict__ cursor, int* __restrict__ adj_src,
                       float* __restrict__ adj_ea) {
    int e = blockIdx.x * 256 + threadIdx.x;
    if (e < N_EDGES) {
        int d = ei[N_EDGES + e];
        int pos = atomicAdd(&cursor[d], 1);
        adj_src[pos] = ei[e];
        adj_ea[pos] = ea[e];
    }
}

__global__ void k_prep(const float* __restrict__ We1, const float* __restrict__ ae1,
                       const float* __restrict__ We2, const float* __restrict__ ae2,
                       float* __restrict__ wedot) {
    int t = threadIdx.x;
    if (t < HEADS) {
        float a = 0.f;
        for (int c = 0; c < HID; ++c) a += We1[t * HID + c] * ae1[t * HID + c];
        wedot[t] = a;
    } else if (t == HEADS) {
        float a = 0.f;
        for (int c = 0; c < HID; ++c) a += We2[c] * ae2[c];
        wedot[HEADS] = a;
    }
}

// pack W2 (256x32 f32) into bf16 MFMA-B fragment order:
// W2p[((k>>3)*32 + col)*8 + (k&7)] = bf16(W2[k][col])
__global__ void k_packW2(const float* __restrict__ W2, unsigned short* __restrict__ W2p) {
    int i = blockIdx.x * 256 + threadIdx.x;   // i = k*32 + col
    if (i >= D1 * HID) return;
    int k = i >> 5, col = i & 31;
    W2p[(((k >> 3) * 32) + col) * 8 + (k & 7)] = f2bf(W2[i]);
}

// ---------------- conv1 ----------------

// x @ W1 -> h1 (bf16). Block: 16 nodes x 256 cols.
__global__ __launch_bounds__(256) void k_gemm1(const float* __restrict__ x,
                                               const float* __restrict__ W1,
                                               unsigned short* __restrict__ h1) {
    __shared__ float xs[16 * F_IN];
    int n0 = blockIdx.x * 16;
    for (int i = threadIdx.x; i < 16 * F_IN; i += 256)
        xs[i] = x[(size_t)n0 * F_IN + i];
    __syncthreads();
    int col = threadIdx.x;
    float acc[16];
    #pragma unroll
    for (int r = 0; r < 16; ++r) acc[r] = 0.f;
    for (int k = 0; k < F_IN; ++k) {
        float w = W1[k * D1 + col];
        #pragma unroll
        for (int r = 0; r < 16; ++r) acc[r] += xs[r * F_IN + k] * w;
    }
    #pragma unroll
    for (int r = 0; r < 16; ++r)
        h1[(size_t)(n0 + r) * D1 + col] = f2bf(acc[r]);
}

// per-node attention logits from bf16 h1; 1 wave per node, 4 nodes/block
__global__ __launch_bounds__(256) void k_alpha1(const unsigned short* __restrict__ h1,
                                                const float* __restrict__ as1,
                                                const float* __restrict__ ad1,
                                                float* __restrict__ al_s,
                                                float* __restrict__ al_d) {
    int wid = threadIdx.x >> 6, l = threadIdx.x & 63;
    int n = blockIdx.x * 4 + wid;
    if (n >= N_NODES) return;
    ushort4 p = *(const ushort4*)(h1 + (size_t)n * D1 + l * 4);
    int c = l * 4;
    float v0 = bf2f(p.x), v1 = bf2f(p.y), v2 = bf2f(p.z), v3 = bf2f(p.w);
    float vs = v0 * as1[c] + v1 * as1[c + 1] + v2 * as1[c + 2] + v3 * as1[c + 3];
    float vd = v0 * ad1[c] + v1 * ad1[c + 1] + v2 * ad1[c + 2] + v3 * ad1[c + 3];
    #pragma unroll
    for (int off = 1; off < 8; off <<= 1) {
        vs += __shfl_xor(vs, off, 64);
        vd += __shfl_xor(vd, off, 64);
    }
    if ((l & 7) == 0) {
        al_s[n * HEADS + (l >> 3)] = vs;
        al_d[n * HEADS + (l >> 3)] = vd;
    }
}

// aggregation conv1: 1 wave per node, lane l handles channels 4l..4l+3
__global__ __launch_bounds__(256) void k_aggr1(
        const int* __restrict__ row_off, const int* __restrict__ deg,
        const int* __restrict__ adj_src, const float* __restrict__ adj_ea,
        const float* __restrict__ easum, const unsigned short* __restrict__ h1,
        const float* __restrict__ al_s, const float* __restrict__ al_d,
        const float* __restrict__ wedot,
        const float* __restrict__ b1, const float* __restrict__ g1,
        const float* __restrict__ be1, const float* __restrict__ m1,
        const float* __restrict__ v1, unsigned short* __restrict__ h1p) {
    int wid = threadIdx.x >> 6, l = threadIdx.x & 63;
    int n = blockIdx.x * 4 + wid;
    if (n >= N_NODES) return;
    int h = l >> 3;
    float wd = wedot[h];
    float dn = al_d[n * HEADS + h];
    int r0 = row_off[n], cnt = deg[n];
    float a0 = 0.f, a1 = 0.f, a2 = 0.f, a3 = 0.f, den = 0.f;
    for (int base = 0; base < cnt; base += 64) {
        int m = cnt - base; if (m > 64) m = 64;
        int sl = 0; float el = 0.f;
        if (l < m) {
            sl = adj_src[r0 + base + l];
            el = adj_ea[r0 + base + l];
        }
        for (int i = 0; i < m; ++i) {
            int s = __shfl(sl, i, 64);
            float eav = __shfl(el, i, 64);
            float a = al_s[s * HEADS + h] + dn + eav * wd;
            a = a > 0.f ? a : 0.2f * a;
            float w = __expf(a);
            den += w;
            ushort4 p = *(const ushort4*)(h1 + (size_t)s * D1 + l * 4);
            a0 += w * bf2f(p.x); a1 += w * bf2f(p.y);
            a2 += w * bf2f(p.z); a3 += w * bf2f(p.w);
        }
    }
    {   // self loop, attr = mean of incoming (0 if none)
        float la = easum[n] / (float)(cnt > 0 ? cnt : 1);
        float a = al_s[n * HEADS + h] + dn + la * wd;
        a = a > 0.f ? a : 0.2f * a;
        float w = __expf(a);
        den += w;
        ushort4 p = *(const ushort4*)(h1 + (size_t)n * D1 + l * 4);
        a0 += w * bf2f(p.x); a1 += w * bf2f(p.y);
        a2 += w * bf2f(p.z); a3 += w * bf2f(p.w);
    }
    float inv = 1.f / den;
    int c = l * 4;
    ushort4 o;
    float acc[4] = {a0, a1, a2, a3};
    unsigned short* po = (unsigned short*)&o;
    #pragma unroll
    for (int j = 0; j < 4; ++j) {
        float ov = acc[j] * inv + b1[c + j];
        float sc = g1[c + j] * __frsqrt_rn(v1[c + j] + EPSV);
        float y = (ov - m1[c + j]) * sc + be1[c + j];
        po[j] = f2bf(y > 0.f ? y : 0.f);
    }
    *(ushort4*)(h1p + (size_t)n * D1 + c) = o;
}

// ---------------- conv2 ----------------

// h1p(bf16) @ W2p(bf16, frag-packed) -> h2 (f32) via MFMA, fused alpha2.
// One wave = 16 nodes x 32 cols. 3125 waves cover N exactly.
__global__ __launch_bounds__(256) void k_gemm2(const unsigned short* __restrict__ h1p,
                                               const unsigned short* __restrict__ W2p,
                                               const float* __restrict__ as2,
                                               const float* __restrict__ ad2,
                                               float* __restrict__ h2,
                                               float* __restrict__ al_s2,
                                               float* __restrict__ al_d2) {
    int wid = threadIdx.x >> 6, l = threadIdx.x & 63;
    int wave = blockIdx.x * 4 + wid;
    if (wave >= N_NODES / 16) return;
    int n0 = wave * 16;
    int g = l >> 4;        // k-subgroup 0..3
    int c16 = l & 15;      // col within 16 / A-row within 16
    f32x4 acc0 = {0.f, 0.f, 0.f, 0.f};
    f32x4 acc1 = {0.f, 0.f, 0.f, 0.f};
    const short8* ap = (const short8*)(h1p + (size_t)(n0 + c16) * D1 + g * 8);
    const short8* wp = (const short8*)W2p;
    #pragma unroll
    for (int ks = 0; ks < 8; ++ks) {
        short8 afrag = ap[ks * 4];                     // +ks*32 bf16
        short8 b0 = wp[(ks * 4 + g) * 32 + c16];
        short8 b1 = wp[(ks * 4 + g) * 32 + 16 + c16];
        acc0 = __builtin_amdgcn_mfma_f32_16x16x32_bf16(afrag, b0, acc0, 0, 0, 0);
        acc1 = __builtin_amdgcn_mfma_f32_16x16x32_bf16(afrag, b1, acc1, 0, 0, 0);
    }
    // C layout: col = lane&15, row = (lane>>4)*4 + reg
    float s0 = as2[c16], s1 = as2[16 + c16];
    float d0 = ad2[c16], d1 = ad2[16 + c16];
    float ps[4], pd[4];
    #pragma unroll
    for (int r = 0; r < 4; ++r) {
        int node = n0 + g * 4 + r;
        h2[(size_t)node * HID + c16]      = acc0[r];
        h2[(size_t)node * HID + 16 + c16] = acc1[r];
        ps[r] = acc0[r] * s0 + acc1[r] * s1;
        pd[r] = acc0[r] * d0 + acc1[r] * d1;
    }
    #pragma unroll
    for (int off = 1; off < 16; off <<= 1) {
        #pragma unroll
        for (int r = 0; r < 4; ++r) {
            ps[r] += __shfl_xor(ps[r], off, 64);
            pd[r] += __shfl_xor(pd[r], off, 64);
        }
    }
    if (c16 == 0) {
        #pragma unroll
        for (int r = 0; r < 4; ++r) {
            int node = n0 + g * 4 + r;
            al_s2[node] = ps[r];
            al_d2[node] = pd[r];
        }
    }
}

// aggregation conv2: 1 wave per node, 2 edges/iter (half-waves), no atomics.
__global__ __launch_bounds__(256) void k_aggr2(
        const int* __restrict__ row_off, const int* __restrict__ deg,
        const int* __restrict__ adj_src, const float* __restrict__ adj_ea,
        const float* __restrict__ easum, const float* __restrict__ h2,
        const float* __restrict__ al_s2, const float* __restrict__ al_d2,
        const float* __restrict__ wedot,
        const float* __restrict__ b2, const float* __restrict__ g2,
        const float* __restrict__ be2, const float* __restrict__ m2,
        const float* __restrict__ v2, float* __restrict__ h2p) {
    int wid = threadIdx.x >> 6, l = threadIdx.x & 63;
    int n = blockIdx.x * 4 + wid;
    if (n >= N_NODES) return;
    int c = l & 31, half = l >> 5;
    float wd = wedot[HEADS];
    float dn = al_d2[n];
    int r0 = row_off[n], cnt = deg[n];
    float acc = 0.f, den = 0.f;
    for (int base = 0; base < cnt; base += 64) {
        int m = cnt - base; if (m > 64) m = 64;
        int sl = 0; float el = 0.f;
        if (l < m) {
            sl = adj_src[r0 + base + l];
            el = adj_ea[r0 + base + l];
        }
        for (int i = 0; i < m; i += 2) {
            int j = i + half;
            bool ok = j < m;
            int jj = ok ? j : 0;
            int s = __shfl(sl, jj, 64);
            float eav = __shfl(el, jj, 64);
            if (ok) {
                float a = al_s2[s] + dn + eav * wd;
                a = a > 0.f ? a : 0.2f * a;
                float w = __expf(a);
                den += w;
                acc += w * h2[(size_t)s * HID + c];
            }
        }
    }
    // merge the two half-wave partial sums
    acc += __shfl_xor(acc, 32, 64);
    den += __shfl_xor(den, 32, 64);
    {   // self loop (each lane adds exactly once)
        float la = easum[n] / (float)(cnt > 0 ? cnt : 1);
        float a = al_s2[n] + dn + la * wd;
        a = a > 0.f ? a : 0.2f * a;
        float w = __expf(a);
        den += w;
        acc += w * h2[(size_t)n * HID + c];
    }
    float o = acc / den + b2[c];
    float sc = g2[c] * __frsqrt_rn(v2[c] + EPSV);
    float y = (o - m2[c]) * sc + be2[c];
    y = y > 0.f ? y : 0.f;
    if (half == 0) h2p[(size_t)n * HID + c] = y;
}

// pool (mean over sorted batch segments) + fc, one block per graph
__global__ __launch_bounds__(64) void k_poolfc(const float* __restrict__ h2p,
                                               const int* __restrict__ batch,
                                               const float* __restrict__ fcW,
                                               const float* __restrict__ fcb,
                                               float* __restrict__ out) {
    int g = blockIdx.x;
    int l = threadIdx.x;
    auto lb = [&](int key) {
        int lo = 0, hi = N_NODES;
        while (lo < hi) {
            int mid = (lo + hi) >> 1;
            if (batch[mid] < key) lo = mid + 1; else hi = mid;
        }
        return lo;
    };
    int s0 = lb(g), s1 = lb(g + 1);
    int c = l & 31, half = l >> 5;
    float acc = 0.f;
    for (int r = s0 + half; r < s1; r += 2)
        acc += h2p[(size_t)r * HID + c];
    acc += __shfl_xor(acc, 32, 64);
    int cn = s1 - s0;
    float mean = acc / (float)(cn > 0 ? cn : 1);
    float p = mean * fcW[c];
    #pragma unroll
    for (int off = 1; off < 32; off <<= 1) p += __shfl_xor(p, off, 64);
    if (l == 0) out[g] = p + fcb[0];
}

// ---------------- launch ----------------

extern "C" void kernel_launch(void* const* d_in, const int* in_sizes, int n_in,
                              void* d_out, int out_size, void* d_ws, size_t ws_size,
                              hipStream_t stream) {
    const float* x    = (const float*)d_in[0];
    const int*   ei   = (const int*)  d_in[1];
    const float* ea   = (const float*)d_in[2];
    const int*   batch= (const int*)  d_in[3];
    const float* W1   = (const float*)d_in[4];
    const float* We1  = (const float*)d_in[5];
    const float* as1  = (const float*)d_in[6];
    const float* ad1  = (const float*)d_in[7];
    const float* ae1  = (const float*)d_in[8];
    const float* b1   = (const float*)d_in[9];
    const float* g1   = (const float*)d_in[10];
    const float* be1  = (const float*)d_in[11];
    const float* m1   = (const float*)d_in[12];
    const float* v1   = (const float*)d_in[13];
    const float* W2   = (const float*)d_in[14];
    const float* We2  = (const float*)d_in[15];
    const float* as2  = (const float*)d_in[16];
    const float* ad2  = (const float*)d_in[17];
    const float* ae2  = (const float*)d_in[18];
    const float* b2   = (const float*)d_in[19];
    const float* g2   = (const float*)d_in[20];
    const float* be2  = (const float*)d_in[21];
    const float* m2   = (const float*)d_in[22];
    const float* v2   = (const float*)d_in[23];
    const float* fcW  = (const float*)d_in[24];
    const float* fcb  = (const float*)d_in[25];
    float* out = (float*)d_out;

    char* ws = (char*)d_ws;
    size_t off = 0;
    auto alloc = [&](size_t bytes) -> void* {
        void* p = ws + off;
        off += (bytes + 255) & ~(size_t)255;
        return p;
    };
    int*   deg     = (int*)  alloc((size_t)N_NODES * 4);
    float* easum   = (float*)alloc((size_t)N_NODES * 4);
    int*   row_off = (int*)  alloc((size_t)N_NODES * 4);
    int*   cursor  = (int*)  alloc((size_t)N_NODES * 4);
    int*   adj_src = (int*)  alloc((size_t)N_EDGES * 4);
    float* adj_ea  = (float*)alloc((size_t)N_EDGES * 4);
    float* al_s1   = (float*)alloc((size_t)N_NODES * HEADS * 4);
    float* al_d1   = (float*)alloc((size_t)N_NODES * HEADS * 4);
    float* al_s2   = (float*)alloc((size_t)N_NODES * 4);
    float* al_d2   = (float*)alloc((size_t)N_NODES * 4);
    float* wedot   = (float*)alloc(16 * 4);
    int*   partials= (int*)  alloc(64 * 4);
    int*   poff    = (int*)  alloc(64 * 4);
    unsigned short* W2p = (unsigned short*)alloc((size_t)D1 * HID * 2);
    unsigned short* h1  = (unsigned short*)alloc((size_t)N_NODES * D1 * 2);
    unsigned short* h1p = (unsigned short*)alloc((size_t)N_NODES * D1 * 2);
    float* h2      = (float*)alloc((size_t)N_NODES * HID * 4);
    float* h2p     = (float*)alloc((size_t)N_NODES * HID * 4);
    (void)ws_size; (void)in_sizes; (void)n_in; (void)out_size;

    hipMemsetAsync(deg,   0, (size_t)N_NODES * 4, stream);
    hipMemsetAsync(easum, 0, (size_t)N_NODES * 4, stream);

    k_deg<<<(N_EDGES + 255) / 256, 256, 0, stream>>>(ei, ea, deg, easum);
    k_partial<<<NCHUNK, 256, 0, stream>>>(deg, partials);
    k_scanp<<<1, 64, 0, stream>>>(partials, poff);
    k_scanc<<<NCHUNK, 256, 0, stream>>>(deg, poff, row_off, cursor);
    k_fill<<<(N_EDGES + 255) / 256, 256, 0, stream>>>(ei, ea, cursor, adj_src, adj_ea);
    k_prep<<<1, 64, 0, stream>>>(We1, ae1, We2, ae2, wedot);
    k_packW2<<<(D1 * HID + 255) / 256, 256, 0, stream>>>(W2, W2p);

    k_gemm1<<<N_NODES / 16, 256, 0, stream>>>(x, W1, h1);
    k_alpha1<<<(N_NODES + 3) / 4, 256, 0, stream>>>(h1, as1, ad1, al_s1, al_d1);
    k_aggr1<<<(N_NODES + 3) / 4, 256, 0, stream>>>(row_off, deg, adj_src, adj_ea, easum,
                                                   h1, al_s1, al_d1, wedot, b1, g1, be1,
                                                   m1, v1, h1p);

    k_gemm2<<<(N_NODES / 16 + 3) / 4, 256, 0, stream>>>(h1p, W2p, as2, ad2, h2, al_s2, al_d2);
    k_aggr2<<<(N_NODES + 3) / 4, 256, 0, stream>>>(row_off, deg, adj_src, adj_ea, easum,
                                                   h2, al_s2, al_d2, wedot, b2, g2, be2,
                                                   m2, v2, h2p);
    k_poolfc<<<G_GRAPHS, 64, 0, stream>>>(h2p, batch, fcW, fcb, out);
}